// Round 4
// baseline (254.565 us; speedup 1.0000x reference)
//
#include <hip/hip_runtime.h>

// ---------------------------------------------------------------------------
// context = softmax((q@Wq+bq)(k@Wk+bk)^T / 32) @ (v@Wv+bv)
// S=4096, H=D=1024. fp32 in/out, bf16 MFMA internally.
//
// GEMM core (gemm256): 256x256 tile, 512 threads (8 waves, 2x4), K processed
// in K=64 TILES (2 chunks of 32) through a 4-chunk LDS ring (128KB).
// m201 rhythm: 4 phases per K-tile, each phase = one C-quadrant x K=64
// (16 MFMA). Reads per phase: 12 / 4 / 8 / 0 (A,B halves kept in regs).
// Staging (race-free retime, round-4 fix): a slot region is staged only
// AFTER the phase-closing barrier that drains its last reader:
//   B(2t)/B(2t+1) last read in P1  -> STAGE_B(2t+4), STAGE_B(2t+5) in P2
//   A(2t)/A(2t+1) last read in P2  -> STAGE_A(2t+4), STAGE_A(2t+5) in P3
// (Round 3 staged B(2t+4) inside P1 while P1 was still reading that slot's
//  B-half1 -> nondeterministic corruption. Fixed.)
// ONE counted s_waitcnt vmcnt(8) per K-tile (never 0 in main loop, T4);
// its wait target was issued a full tile (~3400cy) earlier -> latency hidden.
//
// LDS bank swizzle (T2, both-sides-or-neither): logical 16B col k8 of row r
// lives at physical col k8 ^ ((r>>1)&3). Reads use lq ^ ((lr>>1)&3) (lane-
// constant); staging keeps the linear global_load_lds dest and pre-swizzles
// the per-lane GLOBAL k-offset: (l&3) ^ ((l>>3)&3). Verified conflict-free
// (round 2: SQ_LDS_BANK_CONFLICT = 0).
//
// ws layout (MB):
//   [ 0, 6)  Wt  bf16 [3][1024][1024]      (W^T, per projection)
//   [ 6,30)  xb  bf16 [3][4096][1024]      (q,k,v cast)
//   [30,54)  pr  bf16 [3][4096][1024]      (Q,K,Vn projections; z-contiguous)
//   [46,78)  S   bf16 [4096][4096]         (overwrites dead Vn after transpose)
//   [78,86)  Vt  bf16 [1024][4096]
//   [ 0,16)  p1, [16,32) p2  fp32 partials (dead Wt/xb region at PV time)
//   [86,102) p3 fp32 partial               (only if ws_size >= 102MB -> SK=4)
// ---------------------------------------------------------------------------

typedef short short4v __attribute__((ext_vector_type(4)));
typedef short short8  __attribute__((ext_vector_type(8)));
typedef float f32x4   __attribute__((ext_vector_type(4)));

#define MFMA16 __builtin_amdgcn_mfma_f32_16x16x32_bf16

__device__ __forceinline__ short f2bf(float f) {
    union { float f; unsigned u; } x; x.f = f;
    unsigned r = (x.u + 0x7FFFu + ((x.u >> 16) & 1u)) >> 16;  // RNE
    return (short)r;
}
__device__ __forceinline__ float bf2f(short s) {
    union { unsigned u; float f; } x;
    x.u = ((unsigned)(unsigned short)s) << 16; return x.f;
}
__device__ __forceinline__ void store_out(short* p, float v) { *p = f2bf(v); }
__device__ __forceinline__ void store_out(float* p, float v) { *p = v; }

// async global->LDS, 16B/lane. LDS dest = wave-uniform base + lane*16.
__device__ __forceinline__ void gl2lds(const short* g, short* l) {
    __builtin_amdgcn_global_load_lds(
        (const __attribute__((address_space(1))) void*)g,
        (__attribute__((address_space(3))) void*)l, 16, 0, 0);
}

// --- W[k][n] fp32 -> Wt[z][n][k] bf16 ------------------------------------
__global__ __launch_bounds__(256) void prep_w(
    const float* __restrict__ W0, const float* __restrict__ W1,
    const float* __restrict__ W2, short* __restrict__ Wt)
{
    __shared__ float tile[64][65];
    const float* W = blockIdx.z == 0 ? W0 : (blockIdx.z == 1 ? W1 : W2);
    short* T = Wt + (size_t)blockIdx.z * 1048576;
    const int c0 = blockIdx.x * 64;
    const int r0 = blockIdx.y * 64;
    const int tx = threadIdx.x & 63;
    const int ty = threadIdx.x >> 6;
    #pragma unroll
    for (int p = 0; p < 16; ++p) {
        int r = ty + p * 4;
        tile[r][tx] = W[(size_t)(r0 + r) * 1024 + c0 + tx];
    }
    __syncthreads();
    #pragma unroll
    for (int p = 0; p < 16; ++p) {
        int r = ty + p * 4;
        T[(size_t)(c0 + r) * 1024 + r0 + tx] = f2bf(tile[tx][r]);
    }
}

// --- q,k,v fp32 -> xb bf16 -----------------------------------------------
__global__ __launch_bounds__(256) void cast_qkv(
    const float* __restrict__ q, const float* __restrict__ k,
    const float* __restrict__ v, short* __restrict__ xb)
{
    const float* src = blockIdx.z == 0 ? q : (blockIdx.z == 1 ? k : v);
    short* dst = xb + (size_t)blockIdx.z * 4194304;
    for (int i = blockIdx.x * 256 + threadIdx.x; i < 1048576; i += 256 * 1024) {
        float4 f = ((const float4*)src)[i];
        short4v o;
        o[0] = f2bf(f.x); o[1] = f2bf(f.y); o[2] = f2bf(f.z); o[3] = f2bf(f.w);
        ((short4v*)dst)[i] = o;
    }
}

// --- Vn bf16 [4096][1024] -> Vt bf16 [1024][4096] -------------------------
__global__ __launch_bounds__(256) void transpose_v(
    const short* __restrict__ src, short* __restrict__ dst)
{
    __shared__ short t[64][65];
    const int c0 = blockIdx.x * 64;   // src col block (dst row block)
    const int r0 = blockIdx.y * 64;   // src row block
    const int tx = threadIdx.x & 63;
    const int ty = threadIdx.x >> 6;
    #pragma unroll
    for (int p = 0; p < 16; ++p) {
        const int r = p * 4 + ty;
        t[r][tx] = src[(size_t)(r0 + r) * 1024 + c0 + tx];
    }
    __syncthreads();
    #pragma unroll
    for (int p = 0; p < 16; ++p) {
        const int r = p * 4 + ty;
        dst[(size_t)(c0 + r) * 4096 + r0 + tx] = t[tx][r];
    }
}

// --- bf16 GEMM core: C = scale*(A @ Bt^T) [+ bias] ------------------------
// 256x256 tile, 8 waves (2Mx4N), 4-chunk LDS ring, m201 4-phase K-tiles.
// MODE 0: plain. MODE 1: z selects {A,Bt,C,bias} (batched projections).
// MODE 2: z is split-K index; C-dst = {C, P1, P2, P3}[z].
template <typename TOut, int MODE>
__global__ __launch_bounds__(512, 2) void gemm256(
    const short* __restrict__ A, const short* __restrict__ Bt,
    const float* __restrict__ b0, const float* __restrict__ b1,
    const float* __restrict__ b2,
    TOut* __restrict__ C, float* __restrict__ P1, float* __restrict__ P2,
    float* __restrict__ P3,
    int M, int N, int lda, int ldb, float scale,
    int nc, int nc_last, int kstep)
{
    // 4 chunk-slots x { A [256 rows][64B] , B [256 rows][64B] } = 128KB
    __shared__ short Lds[65536];

    const int t    = threadIdx.x;
    const int lane = t & 63;
    const int wv   = t >> 6;

    // ---- grid swizzle (XCD L2 locality). HW round-robins bid%8 -> XCD. ---
    int m0, n0;
    {
        const int nb  = gridDim.x;                    // n-tiles
        const int bid = blockIdx.y * nb + blockIdx.x;
        if (nb == 16 && gridDim.y == 16) {
            // 2x4 XCD rectangles: XCD x gets an 8m x 4n block of tiles.
            const int x = bid & 7, i = bid >> 3;
            m0 = ((x & 1) * 8 + (i & 7)) * 256;
            n0 = ((x >> 1) * 4 + (i >> 3)) * 256;
        } else {
            // band swizzle: 8 m-tiles per band, XCD x keeps m == x (mod 8).
            const int band   = bid / (8 * nb);
            const int within = bid - band * 8 * nb;
            m0 = (band * 8 + (within & 7)) * 256;
            n0 = (within >> 3) * 256;
        }
    }

    const float* bias = nullptr;
    int kbeg = 0;
    TOut* Cw = C;
    if constexpr (MODE == 1) {
        const int z = blockIdx.z;
        A  += (size_t)z * M * lda;
        Bt += (size_t)z * N * ldb;
        Cw  = C + (size_t)z * M * N;
        bias = z == 0 ? b0 : (z == 1 ? b1 : b2);
    }
    if constexpr (MODE == 2) {
        const int z = blockIdx.z;
        kbeg = z * kstep;
        if (z == (int)gridDim.z - 1) nc = nc_last;
        Cw = (TOut*)(z == 0 ? (float*)C : (z == 1 ? P1 : (z == 2 ? P2 : P3)));
    }
    (void)b0; (void)b1; (void)b2; (void)P1; (void)P2; (void)P3;
    (void)nc_last; (void)kstep;

    // ---- staging map: per chunk, each wave issues 4 gl2lds (1KB each). ---
    // lane l -> row = wv*16 + (l>>2); global 16B-col pre-swizzled with the
    // same involution the reads use: (l&3) ^ ((l>>3)&3)  [key=(row>>1)&3].
    const int srow = lane >> 2;
    const int skof = ((lane & 3) ^ ((lane >> 3) & 3)) * 8;
    const short* pA0 = A  + (size_t)(m0 + wv * 16 + srow) * lda + kbeg + skof;
    const short* pA1 = pA0 + (size_t)128 * lda;
    const short* pB0 = Bt + (size_t)(n0 + wv * 16 + srow) * ldb + kbeg + skof;
    const short* pB1 = pB0 + (size_t)128 * ldb;
    short* sA0 = Lds + wv * 512;            // wave-uniform LDS bases (shorts)
    short* sA1 = Lds + 4096  + wv * 512;
    short* sB0 = Lds + 8192  + wv * 512;
    short* sB1 = Lds + 12288 + wv * 512;

    // ---- fragment read map (16x16x32: lane = lr + 16*lq) -----------------
    // physical 16B col = lq ^ ((row>>1)&3); row base is a multiple of 16 so
    // the key reduces to (lr>>1)&3 -> lane-constant pointer.
    const int wm = wv >> 2, wn = wv & 3;
    const int lr = lane & 15, lq = lane >> 4;
    const int pcol = lq ^ ((lr >> 1) & 3);
    const short* rdA = Lds + (wm * 128 + lr) * 32 + pcol * 8;
    const short* rdB = Lds + 8192 + (wn * 64 + lr) * 32 + pcol * 8;

    f32x4 acc[8][4];
    #pragma unroll
    for (int i = 0; i < 8; ++i)
        #pragma unroll
        for (int j = 0; j < 4; ++j) { f32x4 z4 = {0.f,0.f,0.f,0.f}; acc[i][j] = z4; }

#define STAGE_A(c) {                                                      \
    const int su_ = (c) & 3;                                              \
    const size_t ko_ = (size_t)(c) * 32;                                  \
    gl2lds(pA0 + ko_, sA0 + su_ * 16384);                                 \
    gl2lds(pA1 + ko_, sA1 + su_ * 16384); }
#define STAGE_B(c) {                                                      \
    const int su_ = (c) & 3;                                              \
    const size_t ko_ = (size_t)(c) * 32;                                  \
    gl2lds(pB0 + ko_, sB0 + su_ * 16384);                                 \
    gl2lds(pB1 + ko_, sB1 + su_ * 16384); }

    // prologue: tiles 0 and 1 (chunks 0-3) in flight; wait tile 0 (8 left).
    STAGE_A(0); STAGE_B(0); STAGE_A(1); STAGE_B(1);
    STAGE_A(2); STAGE_B(2); STAGE_A(3); STAGE_B(3);
    asm volatile("s_waitcnt vmcnt(8)" ::: "memory");
    __builtin_amdgcn_s_barrier();

    const int nt = nc >> 1;   // K-tiles of 64 (nc always even)

    // K-tile t = chunks 2t,2t+1 (slots u0_,u0_+1). Stages target tile t+2;
    // each stage lands only in a slot region whose LAST reads were drained
    // by a phase-closing barrier: B regions (last read P1) staged in P2,
    // A regions (last read P2) staged in P3.
    // vmcnt(8) at tile end = this tile's 8 issues outstanding, i.e. tile
    // t+1 (issued a full tile ago) is complete before its P0 reads it.
#define TILE(t, DOSTAGE, VMN) {                                           \
    const int u0_ = (2 * (t)) & 3;                                        \
    const short* a0_ = rdA + u0_ * 16384;                                 \
    const short* a1_ = a0_ + 16384;                                       \
    const short* b0_ = rdB + u0_ * 16384;                                 \
    const short* b1_ = b0_ + 16384;                                       \
    short8 af[8], bfr[4], bg[4];                                          \
    /* P0: Q(0,0) -- 12 ds_reads (A-half0 + B-half0, both ksteps) */      \
    _Pragma("unroll") for (int mi = 0; mi < 4; ++mi) {                    \
        af[mi * 2]     = *(const short8*)(a0_ + mi * 512);                \
        af[mi * 2 + 1] = *(const short8*)(a1_ + mi * 512);                \
    }                                                                     \
    _Pragma("unroll") for (int nj = 0; nj < 2; ++nj) {                    \
        bfr[nj * 2]     = *(const short8*)(b0_ + nj * 512);               \
        bfr[nj * 2 + 1] = *(const short8*)(b1_ + nj * 512);               \
    }                                                                     \
    __builtin_amdgcn_s_barrier();                                         \
    __builtin_amdgcn_s_setprio(1);                                        \
    _Pragma("unroll") for (int mi = 0; mi < 4; ++mi)                      \
        _Pragma("unroll") for (int nj = 0; nj < 2; ++nj) {                \
            acc[mi][nj] = MFMA16(af[mi*2],   bfr[nj*2],   acc[mi][nj], 0,0,0); \
            acc[mi][nj] = MFMA16(af[mi*2+1], bfr[nj*2+1], acc[mi][nj], 0,0,0); \
        }                                                                 \
    __builtin_amdgcn_s_setprio(0);                                        \
    __builtin_amdgcn_s_barrier();                                         \
    /* P1: Q(0,1) -- 4 ds_reads (B-half1); no stage (slot still read) */  \
    _Pragma("unroll") for (int nj = 0; nj < 2; ++nj) {                    \
        bg[nj * 2]     = *(const short8*)(b0_ + (2 + nj) * 512);          \
        bg[nj * 2 + 1] = *(const short8*)(b1_ + (2 + nj) * 512);          \
    }                                                                     \
    __builtin_amdgcn_s_barrier();                                         \
    __builtin_amdgcn_s_setprio(1);                                        \
    _Pragma("unroll") for (int mi = 0; mi < 4; ++mi)                      \
        _Pragma("unroll") for (int nj = 0; nj < 2; ++nj) {                \
            acc[mi][2+nj] = MFMA16(af[mi*2],   bg[nj*2],   acc[mi][2+nj], 0,0,0); \
            acc[mi][2+nj] = MFMA16(af[mi*2+1], bg[nj*2+1], acc[mi][2+nj], 0,0,0); \
        }                                                                 \
    __builtin_amdgcn_s_setprio(0);                                        \
    __builtin_amdgcn_s_barrier();                                         \
    /* P2: Q(1,0) -- 8 ds_reads (A-half1); stage B(2t+4), B(2t+5)         \
       (B regions' last reads were P1, drained by P1's barrier) */        \
    _Pragma("unroll") for (int mi = 0; mi < 4; ++mi) {                    \
        af[mi * 2]     = *(const short8*)(a0_ + (4 + mi) * 512);          \
        af[mi * 2 + 1] = *(const short8*)(a1_ + (4 + mi) * 512);          \
    }                                                                     \
    if (DOSTAGE) { STAGE_B(2 * (t) + 4); STAGE_B(2 * (t) + 5); }          \
    __builtin_amdgcn_s_barrier();                                         \
    __builtin_amdgcn_s_setprio(1);                                        \
    _Pragma("unroll") for (int mi = 0; mi < 4; ++mi)                      \
        _Pragma("unroll") for (int nj = 0; nj < 2; ++nj) {                \
            acc[4+mi][nj] = MFMA16(af[mi*2],   bfr[nj*2],   acc[4+mi][nj], 0,0,0); \
            acc[4+mi][nj] = MFMA16(af[mi*2+1], bfr[nj*2+1], acc[4+mi][nj], 0,0,0); \
        }                                                                 \
    __builtin_amdgcn_s_setprio(0);                                        \
    __builtin_amdgcn_s_barrier();                                         \
    /* P3: Q(1,1) -- 0 ds_reads; stage A(2t+4), A(2t+5)                   \
       (A regions' last reads were P2, drained by P2's barrier) */        \
    if (DOSTAGE) { STAGE_A(2 * (t) + 4); STAGE_A(2 * (t) + 5); }          \
    __builtin_amdgcn_s_barrier();                                         \
    __builtin_amdgcn_s_setprio(1);                                        \
    _Pragma("unroll") for (int mi = 0; mi < 4; ++mi)                      \
        _Pragma("unroll") for (int nj = 0; nj < 2; ++nj) {                \
            acc[4+mi][2+nj] = MFMA16(af[mi*2],   bg[nj*2],   acc[4+mi][2+nj], 0,0,0); \
            acc[4+mi][2+nj] = MFMA16(af[mi*2+1], bg[nj*2+1], acc[4+mi][2+nj], 0,0,0); \
        }                                                                 \
    __builtin_amdgcn_s_setprio(0);                                        \
    if ((VMN) == 8)      asm volatile("s_waitcnt vmcnt(8)" ::: "memory"); \
    else if ((VMN) == 0) asm volatile("s_waitcnt vmcnt(0)" ::: "memory"); \
    if ((VMN) >= 0) __builtin_amdgcn_s_barrier(); }

    #pragma unroll 2
    for (int tt = 0; tt < nt - 2; ++tt) TILE(tt, 1, 8);
    TILE(nt - 2, 0, 0);
    TILE(nt - 1, 0, -1);
#undef TILE
#undef STAGE_A
#undef STAGE_B

    // ---- epilogue: C/D layout col=lane&15, row=(lane>>4)*4+reg -----------
    #pragma unroll
    for (int i = 0; i < 8; ++i) {
        const int crow = m0 + wm * 128 + i * 16 + lq * 4;
        #pragma unroll
        for (int j = 0; j < 4; ++j) {
            const int ccol = n0 + wn * 64 + j * 16 + lr;
            float bb = 0.f;
            if constexpr (MODE == 1) bb = bias[ccol];
            #pragma unroll
            for (int r = 0; r < 4; ++r) {
                float val = acc[i][j][r] * scale + bb;
                store_out(&Cw[(size_t)(crow + r) * N + ccol], val);
            }
        }
    }
}

// --- row softmax in place over bf16 S[4096][4096] -------------------------
__global__ __launch_bounds__(256) void softmax_bf16(short* __restrict__ S)
{
    const int row = blockIdx.x;
    short8* r8 = (short8*)(S + (size_t)row * 4096);
    const int t = threadIdx.x;

    float x[16];
    #pragma unroll
    for (int i = 0; i < 2; ++i) {
        short8 raw = r8[t + 256 * i];
        #pragma unroll
        for (int j = 0; j < 8; ++j) x[8 * i + j] = bf2f(raw[j]);
    }
    float m = -1e30f;
    #pragma unroll
    for (int i = 0; i < 16; ++i) m = fmaxf(m, x[i]);
    #pragma unroll
    for (int off = 32; off > 0; off >>= 1) m = fmaxf(m, __shfl_xor(m, off));

    __shared__ float redm[4], reds[4];
    const int wv = t >> 6;
    if ((t & 63) == 0) redm[wv] = m;
    __syncthreads();
    m = fmaxf(fmaxf(redm[0], redm[1]), fmaxf(redm[2], redm[3]));

    float s = 0.f;
    #pragma unroll
    for (int i = 0; i < 16; ++i) { x[i] = __expf(x[i] - m); s += x[i]; }
    #pragma unroll
    for (int off = 32; off > 0; off >>= 1) s += __shfl_xor(s, off);
    if ((t & 63) == 0) reds[wv] = s;
    __syncthreads();
    s = reds[0] + reds[1] + reds[2] + reds[3];
    const float inv = 1.f / s;

    #pragma unroll
    for (int i = 0; i < 2; ++i) {
        short8 o;
        #pragma unroll
        for (int j = 0; j < 8; ++j) o[j] = f2bf(x[8 * i + j] * inv);
        r8[t + 256 * i] = o;
    }
}

// --- out += p1 + p2 (+ p3) (split-K combine, in place) --------------------
__global__ __launch_bounds__(256) void combine(
    float* __restrict__ out, const float* __restrict__ a,
    const float* __restrict__ b, const float* __restrict__ c, int np)
{
    for (int i = blockIdx.x * 256 + threadIdx.x; i < 1048576; i += 256 * 1024) {
        float4 o = ((const float4*)out)[i];
        float4 x = ((const float4*)a)[i];
        float4 y = ((const float4*)b)[i];
        o.x += x.x + y.x; o.y += x.y + y.y;
        o.z += x.z + y.z; o.w += x.w + y.w;
        if (np == 3) {
            float4 w = ((const float4*)c)[i];
            o.x += w.x; o.y += w.y; o.z += w.z; o.w += w.w;
        }
        ((float4*)out)[i] = o;
    }
}

extern "C" void kernel_launch(void* const* d_in, const int* in_sizes, int n_in,
                              void* d_out, int out_size, void* d_ws, size_t ws_size,
                              hipStream_t stream)
{
    const float* q  = (const float*)d_in[0];
    const float* k  = (const float*)d_in[1];
    const float* v  = (const float*)d_in[2];
    const float* Wq = (const float*)d_in[3];
    const float* bq = (const float*)d_in[4];
    const float* Wk = (const float*)d_in[5];
    const float* bk = (const float*)d_in[6];
    const float* Wv = (const float*)d_in[7];
    const float* bv = (const float*)d_in[8];
    float* out = (float*)d_out;

    char* ws = (char*)d_ws;
    const size_t MB = 1ull << 20;
    short* Wt = (short*)(ws + 0);           // 3 x 1M shorts
    short* xb = (short*)(ws + 6 * MB);      // 3 x 4M shorts
    short* pr = (short*)(ws + 30 * MB);     // 3 x 4M shorts: Q, K, Vn
    short* S  = (short*)(ws + 46 * MB);     // 16M shorts (overwrites dead Vn)
    short* Vt = (short*)(ws + 78 * MB);     // 4M shorts
    float* p1 = (float*)(ws + 0);           // dead Wt/xb region by PV time
    float* p2 = (float*)(ws + 16 * MB);
    float* p3 = (float*)(ws + 86 * MB);     // extra space, if available
    const int SK = (ws_size >= 102 * MB) ? 4 : 3;

    // 1) W^T + cast, q/k/v cast
    prep_w<<<dim3(16, 16, 3), 256, 0, stream>>>(Wq, Wk, Wv, Wt);
    cast_qkv<<<dim3(1024, 1, 3), 256, 0, stream>>>(q, k, v, xb);
    // 2) projections: Q,K,Vn -> pr (z-batched)
    gemm256<short, 1><<<dim3(4, 16, 3), 512, 0, stream>>>(
        xb, Wt, bq, bk, bv, pr, nullptr, nullptr, nullptr,
        4096, 1024, 1024, 1024, 1.f, 32, 32, 0);
    // 3) Vn -> Vt (then Vn region is dead; S may overwrite it)
    transpose_v<<<dim3(16, 64), 256, 0, stream>>>(pr + 8 * 1024 * 1024, Vt);
    // 4) S = Q K^T / 32
    gemm256<short, 0><<<dim3(16, 16), 512, 0, stream>>>(
        pr, pr + 4 * 1024 * 1024, nullptr, nullptr, nullptr, S,
        nullptr, nullptr, nullptr,
        4096, 4096, 1024, 1024, 0.03125f, 32, 32, 0);
    // 5) softmax rows in place (bf16)
    softmax_bf16<<<4096, 256, 0, stream>>>(S);
    // 6) partials = P @ V  (split-K; z=0 writes straight to out)
    if (SK == 4) {
        gemm256<float, 2><<<dim3(4, 16, 4), 512, 0, stream>>>(
            S, Vt, nullptr, nullptr, nullptr, out, p1, p2, p3,
            4096, 1024, 4096, 4096, 1.f, 32, 32, 1024);
        combine<<<1024, 256, 0, stream>>>(out, p1, p2, p3, 3);
    } else {
        gemm256<float, 2><<<dim3(4, 16, 3), 512, 0, stream>>>(
            S, Vt, nullptr, nullptr, nullptr, out, p1, p2, nullptr,
            4096, 1024, 4096, 4096, 1.f, 42, 44, 1344);
        combine<<<1024, 256, 0, stream>>>(out, p1, p2, nullptr, 2);
    }
}

// Round 5
// 254.165 us; speedup vs baseline: 1.0016x; 1.0016x over previous
//
#include <hip/hip_runtime.h>

// ---------------------------------------------------------------------------
// context = softmax((q@Wq+bq)(k@Wk+bk)^T / 32) @ (v@Wv+bv)
// S=4096, H=D=1024. fp32 in/out, bf16 MFMA internally.
//
// GEMM core (gemm128): 128x256 tile, 512 threads (8 waves, 2m x 4n of 64x64),
// BK=32 chunks through a 2-slot LDS ring (2 x 24KB = 48KB) -> with
// __launch_bounds__(512,4) (VGPR<=128) this gives 2 BLOCKS/CU (16 waves).
// Rationale (r2-r4 post-mortem): three 256x256 1-block/CU schedule variants
// all sat at MfmaUtil 27% -- barrier/wait stalls unhidden with one block.
// Cross-block overlap (m114; m97-structure's 912 TF at 3 blocks/CU) is the
// robust mechanism: two out-of-phase blocks fill each other's stalls.
// Per chunk: STAGE(c+1) | vmcnt(3) | barrier | 8 ds_read_b128 + 16 MFMA
// (setprio) | barrier.  vmcnt never drains to 0 in the main loop.
//
// LDS bank swizzle (verified conflict-free, round 2): logical 16B col k8 of
// row r lives at physical col k8 ^ ((r>>1)&3). Reads use lq ^ ((lr>>1)&3)
// (lane-constant); staging keeps the linear global_load_lds dest and
// pre-swizzles the per-lane GLOBAL k-offset: (l&3) ^ ((l>>3)&3).
//
// ws layout (MB):
//   [ 0, 6)  Wt  bf16 [3][1024][1024]      (W^T, per projection)
//   [ 6,30)  xb  bf16 [3][4096][1024]      (q,k,v cast)
//   [30,54)  pr  bf16 [3][4096][1024]      (Q,K,Vn projections; z-contiguous)
//   [46,78)  S   bf16 [4096][4096]         (overwrites dead Vn after transpose)
//   [78,86)  Vt  bf16 [1024][4096]
//   [ 0,16)  p1, [16,32) p2  fp32 partials (dead Wt/xb region at PV time)
//   [86,102) p3 fp32 partial               (only if ws_size >= 102MB -> SK=4)
// ---------------------------------------------------------------------------

typedef short short4v __attribute__((ext_vector_type(4)));
typedef short short8  __attribute__((ext_vector_type(8)));
typedef float f32x4   __attribute__((ext_vector_type(4)));

#define MFMA16 __builtin_amdgcn_mfma_f32_16x16x32_bf16

__device__ __forceinline__ short f2bf(float f) {
    union { float f; unsigned u; } x; x.f = f;
    unsigned r = (x.u + 0x7FFFu + ((x.u >> 16) & 1u)) >> 16;  // RNE
    return (short)r;
}
__device__ __forceinline__ float bf2f(short s) {
    union { unsigned u; float f; } x;
    x.u = ((unsigned)(unsigned short)s) << 16; return x.f;
}
__device__ __forceinline__ void store_out(short* p, float v) { *p = f2bf(v); }
__device__ __forceinline__ void store_out(float* p, float v) { *p = v; }

// async global->LDS, 16B/lane. LDS dest = wave-uniform base + lane*16.
__device__ __forceinline__ void gl2lds(const short* g, short* l) {
    __builtin_amdgcn_global_load_lds(
        (const __attribute__((address_space(1))) void*)g,
        (__attribute__((address_space(3))) void*)l, 16, 0, 0);
}

// --- W[k][n] fp32 -> Wt[z][n][k] bf16 ------------------------------------
__global__ __launch_bounds__(256) void prep_w(
    const float* __restrict__ W0, const float* __restrict__ W1,
    const float* __restrict__ W2, short* __restrict__ Wt)
{
    __shared__ float tile[64][65];
    const float* W = blockIdx.z == 0 ? W0 : (blockIdx.z == 1 ? W1 : W2);
    short* T = Wt + (size_t)blockIdx.z * 1048576;
    const int c0 = blockIdx.x * 64;
    const int r0 = blockIdx.y * 64;
    const int tx = threadIdx.x & 63;
    const int ty = threadIdx.x >> 6;
    #pragma unroll
    for (int p = 0; p < 16; ++p) {
        int r = ty + p * 4;
        tile[r][tx] = W[(size_t)(r0 + r) * 1024 + c0 + tx];
    }
    __syncthreads();
    #pragma unroll
    for (int p = 0; p < 16; ++p) {
        int r = ty + p * 4;
        T[(size_t)(c0 + r) * 1024 + r0 + tx] = f2bf(tile[tx][r]);
    }
}

// --- q,k,v fp32 -> xb bf16 -----------------------------------------------
__global__ __launch_bounds__(256) void cast_qkv(
    const float* __restrict__ q, const float* __restrict__ k,
    const float* __restrict__ v, short* __restrict__ xb)
{
    const float* src = blockIdx.z == 0 ? q : (blockIdx.z == 1 ? k : v);
    short* dst = xb + (size_t)blockIdx.z * 4194304;
    for (int i = blockIdx.x * 256 + threadIdx.x; i < 1048576; i += 256 * 1024) {
        float4 f = ((const float4*)src)[i];
        short4v o;
        o[0] = f2bf(f.x); o[1] = f2bf(f.y); o[2] = f2bf(f.z); o[3] = f2bf(f.w);
        ((short4v*)dst)[i] = o;
    }
}

// --- Vn bf16 [4096][1024] -> Vt bf16 [1024][4096] -------------------------
__global__ __launch_bounds__(256) void transpose_v(
    const short* __restrict__ src, short* __restrict__ dst)
{
    __shared__ short t[64][65];
    const int c0 = blockIdx.x * 64;   // src col block (dst row block)
    const int r0 = blockIdx.y * 64;   // src row block
    const int tx = threadIdx.x & 63;
    const int ty = threadIdx.x >> 6;
    #pragma unroll
    for (int p = 0; p < 16; ++p) {
        const int r = p * 4 + ty;
        t[r][tx] = src[(size_t)(r0 + r) * 1024 + c0 + tx];
    }
    __syncthreads();
    #pragma unroll
    for (int p = 0; p < 16; ++p) {
        const int r = p * 4 + ty;
        dst[(size_t)(c0 + r) * 4096 + r0 + tx] = t[tx][r];
    }
}

// --- bf16 GEMM core: C = scale*(A @ Bt^T) [+ bias] ------------------------
// 128x256 tile, 8 waves (2m x 4n, 64x64 each), 2-slot LDS ring, BK=32.
// MODE 0: plain. MODE 1: z selects {A,Bt,C,bias} (batched projections).
// MODE 2: z is split-K index; C-dst = {C, P1, P2, P3}[z].
template <typename TOut, int MODE>
__global__ __launch_bounds__(512, 4) void gemm128(
    const short* __restrict__ A, const short* __restrict__ Bt,
    const float* __restrict__ b0, const float* __restrict__ b1,
    const float* __restrict__ b2,
    TOut* __restrict__ C, float* __restrict__ P1, float* __restrict__ P2,
    float* __restrict__ P3,
    int M, int N, int lda, int ldb, float scale,
    int nc, int nc_last, int kstep)
{
    // 2 slots x { A [128 rows][64B] = 8KB , B [256 rows][64B] = 16KB } = 48KB
    __shared__ short Lds[24576];

    const int t    = threadIdx.x;
    const int lane = t & 63;
    const int wv   = t >> 6;

    // ---- band-swizzled grid (XCD L2 locality): XCD x keeps m==x (mod 8). -
    const int nb  = gridDim.x;                    // n-tiles
    const int bid = blockIdx.y * nb + blockIdx.x;
    const int band   = bid / (8 * nb);
    const int within = bid - band * 8 * nb;
    const int m0 = (band * 8 + (within & 7)) * 128;
    const int n0 = (within >> 3) * 256;

    const float* bias = nullptr;
    int kbeg = 0;
    TOut* Cw = C;
    if constexpr (MODE == 1) {
        const int z = blockIdx.z;
        A  += (size_t)z * M * lda;
        Bt += (size_t)z * N * ldb;
        Cw  = C + (size_t)z * M * N;
        bias = z == 0 ? b0 : (z == 1 ? b1 : b2);
    }
    if constexpr (MODE == 2) {
        const int z = blockIdx.z;
        kbeg = z * kstep;
        if (z == (int)gridDim.z - 1) nc = nc_last;
        Cw = (TOut*)(z == 0 ? (float*)C : (z == 1 ? P1 : (z == 2 ? P2 : P3)));
    }
    (void)b0; (void)b1; (void)b2; (void)P1; (void)P2; (void)P3;
    (void)nc_last; (void)kstep;

    // ---- staging map: per chunk each wave issues 3 gl2lds (1KB each):
    // A rows [wv*16, wv*16+16); B rows [wv*16,+16) and +128.
    // lane l -> row += l>>2, global 16B-col pre-swizzled (l&3)^((l>>3)&3).
    const int srow = lane >> 2;
    const int skof = ((lane & 3) ^ ((lane >> 3) & 3)) * 8;
    const short* pA  = A  + (size_t)(m0 + wv * 16 + srow) * lda + kbeg + skof;
    const short* pB0 = Bt + (size_t)(n0 + wv * 16 + srow) * ldb + kbeg + skof;
    const short* pB1 = pB0 + (size_t)128 * ldb;
    short* sA  = Lds + wv * 512;            // wave-uniform LDS bases (shorts)
    short* sB0 = Lds + 4096 + wv * 512;
    short* sB1 = Lds + 8192 + wv * 512;

    // ---- fragment read map (16x16x32: lane = lr + 16*lq) -----------------
    // physical 16B col = lq ^ ((lr>>1)&3)  (row base multiple of 16).
    const int wm = wv >> 2, wn = wv & 3;    // 2m x 4n wave grid
    const int lr = lane & 15, lq = lane >> 4;
    const int pcol = lq ^ ((lr >> 1) & 3);
    const short* rdA = Lds + (wm * 64 + lr) * 32 + pcol * 8;
    const short* rdB = Lds + 4096 + (wn * 64 + lr) * 32 + pcol * 8;

    f32x4 acc[4][4];
    #pragma unroll
    for (int i = 0; i < 4; ++i)
        #pragma unroll
        for (int j = 0; j < 4; ++j) { f32x4 z4 = {0.f,0.f,0.f,0.f}; acc[i][j] = z4; }

#define STAGE(c) {                                                        \
    const int s_ = (c) & 1;                                               \
    const size_t ko_ = (size_t)(c) * 32;                                  \
    gl2lds(pA  + ko_, sA  + s_ * 12288);                                  \
    gl2lds(pB0 + ko_, sB0 + s_ * 12288);                                  \
    gl2lds(pB1 + ko_, sB1 + s_ * 12288); }

#define COMPUTE(c) {                                                      \
    const short* rA_ = rdA + ((c) & 1) * 12288;                           \
    const short* rB_ = rdB + ((c) & 1) * 12288;                           \
    short8 af[4], bf_[4];                                                 \
    _Pragma("unroll") for (int i = 0; i < 4; ++i)                         \
        af[i] = *(const short8*)(rA_ + i * 512);                          \
    _Pragma("unroll") for (int j = 0; j < 4; ++j)                         \
        bf_[j] = *(const short8*)(rB_ + j * 512);                         \
    __builtin_amdgcn_s_setprio(1);                                        \
    _Pragma("unroll") for (int i = 0; i < 4; ++i)                         \
        _Pragma("unroll") for (int j = 0; j < 4; ++j)                     \
            acc[i][j] = MFMA16(af[i], bf_[j], acc[i][j], 0, 0, 0);        \
    __builtin_amdgcn_s_setprio(0); }

    // prologue: chunk 0 in flight.
    STAGE(0);

    // main loop: stage c+1, retire c (vmcnt(3) = leave c+1's 3 in flight),
    // barrier (all waves' c resident), compute c, barrier (slot (c+1)&1's
    // old reads drained before next iter's STAGE(c+2) overwrites it).
    for (int c = 0; c < nc - 1; ++c) {
        STAGE(c + 1);
        asm volatile("s_waitcnt vmcnt(3)" ::: "memory");
        __builtin_amdgcn_s_barrier();
        COMPUTE(c);
        __builtin_amdgcn_s_barrier();
    }
    // tail: no stage; drain and compute last chunk.
    asm volatile("s_waitcnt vmcnt(0)" ::: "memory");
    __builtin_amdgcn_s_barrier();
    COMPUTE(nc - 1);
#undef COMPUTE
#undef STAGE

    // ---- epilogue: C/D layout col=lane&15, row=(lane>>4)*4+reg -----------
    #pragma unroll
    for (int i = 0; i < 4; ++i) {
        const int crow = m0 + wm * 64 + i * 16 + lq * 4;
        #pragma unroll
        for (int j = 0; j < 4; ++j) {
            const int ccol = n0 + wn * 64 + j * 16 + lr;
            float bb = 0.f;
            if constexpr (MODE == 1) bb = bias[ccol];
            #pragma unroll
            for (int r = 0; r < 4; ++r) {
                float val = acc[i][j][r] * scale + bb;
                store_out(&Cw[(size_t)(crow + r) * N + ccol], val);
            }
        }
    }
}

// --- row softmax in place over bf16 S[4096][4096] -------------------------
__global__ __launch_bounds__(256) void softmax_bf16(short* __restrict__ S)
{
    const int row = blockIdx.x;
    short8* r8 = (short8*)(S + (size_t)row * 4096);
    const int t = threadIdx.x;

    float x[16];
    #pragma unroll
    for (int i = 0; i < 2; ++i) {
        short8 raw = r8[t + 256 * i];
        #pragma unroll
        for (int j = 0; j < 8; ++j) x[8 * i + j] = bf2f(raw[j]);
    }
    float m = -1e30f;
    #pragma unroll
    for (int i = 0; i < 16; ++i) m = fmaxf(m, x[i]);
    #pragma unroll
    for (int off = 32; off > 0; off >>= 1) m = fmaxf(m, __shfl_xor(m, off));

    __shared__ float redm[4], reds[4];
    const int wv = t >> 6;
    if ((t & 63) == 0) redm[wv] = m;
    __syncthreads();
    m = fmaxf(fmaxf(redm[0], redm[1]), fmaxf(redm[2], redm[3]));

    float s = 0.f;
    #pragma unroll
    for (int i = 0; i < 16; ++i) { x[i] = __expf(x[i] - m); s += x[i]; }
    #pragma unroll
    for (int off = 32; off > 0; off >>= 1) s += __shfl_xor(s, off);
    if ((t & 63) == 0) reds[wv] = s;
    __syncthreads();
    s = reds[0] + reds[1] + reds[2] + reds[3];
    const float inv = 1.f / s;

    #pragma unroll
    for (int i = 0; i < 2; ++i) {
        short8 o;
        #pragma unroll
        for (int j = 0; j < 8; ++j) o[j] = f2bf(x[8 * i + j] * inv);
        r8[t + 256 * i] = o;
    }
}

// --- out += p1 + p2 (+ p3) (split-K combine, in place) --------------------
__global__ __launch_bounds__(256) void combine(
    float* __restrict__ out, const float* __restrict__ a,
    const float* __restrict__ b, const float* __restrict__ c, int np)
{
    for (int i = blockIdx.x * 256 + threadIdx.x; i < 1048576; i += 256 * 1024) {
        float4 o = ((const float4*)out)[i];
        float4 x = ((const float4*)a)[i];
        float4 y = ((const float4*)b)[i];
        o.x += x.x + y.x; o.y += x.y + y.y;
        o.z += x.z + y.z; o.w += x.w + y.w;
        if (np == 3) {
            float4 w = ((const float4*)c)[i];
            o.x += w.x; o.y += w.y; o.z += w.z; o.w += w.w;
        }
        ((float4*)out)[i] = o;
    }
}

extern "C" void kernel_launch(void* const* d_in, const int* in_sizes, int n_in,
                              void* d_out, int out_size, void* d_ws, size_t ws_size,
                              hipStream_t stream)
{
    const float* q  = (const float*)d_in[0];
    const float* k  = (const float*)d_in[1];
    const float* v  = (const float*)d_in[2];
    const float* Wq = (const float*)d_in[3];
    const float* bq = (const float*)d_in[4];
    const float* Wk = (const float*)d_in[5];
    const float* bk = (const float*)d_in[6];
    const float* Wv = (const float*)d_in[7];
    const float* bv = (const float*)d_in[8];
    float* out = (float*)d_out;

    char* ws = (char*)d_ws;
    const size_t MB = 1ull << 20;
    short* Wt = (short*)(ws + 0);           // 3 x 1M shorts
    short* xb = (short*)(ws + 6 * MB);      // 3 x 4M shorts
    short* pr = (short*)(ws + 30 * MB);     // 3 x 4M shorts: Q, K, Vn
    short* S  = (short*)(ws + 46 * MB);     // 16M shorts (overwrites dead Vn)
    short* Vt = (short*)(ws + 78 * MB);     // 4M shorts
    float* p1 = (float*)(ws + 0);           // dead Wt/xb region by PV time
    float* p2 = (float*)(ws + 16 * MB);
    float* p3 = (float*)(ws + 86 * MB);     // extra space, if available
    const int SK = (ws_size >= 102 * MB) ? 4 : 3;

    // 1) W^T + cast, q/k/v cast
    prep_w<<<dim3(16, 16, 3), 256, 0, stream>>>(Wq, Wk, Wv, Wt);
    cast_qkv<<<dim3(1024, 1, 3), 256, 0, stream>>>(q, k, v, xb);
    // 2) projections: Q,K,Vn -> pr (z-batched); grid 4n x 32m x 3 = 384 blocks
    gemm128<short, 1><<<dim3(4, 32, 3), 512, 0, stream>>>(
        xb, Wt, bq, bk, bv, pr, nullptr, nullptr, nullptr,
        4096, 1024, 1024, 1024, 1.f, 32, 32, 0);
    // 3) Vn -> Vt (then Vn region is dead; S may overwrite it)
    transpose_v<<<dim3(16, 64), 256, 0, stream>>>(pr + 8 * 1024 * 1024, Vt);
    // 4) S = Q K^T / 32 ; grid 16n x 32m = 512 blocks (2/CU)
    gemm128<short, 0><<<dim3(16, 32), 512, 0, stream>>>(
        pr, pr + 4 * 1024 * 1024, nullptr, nullptr, nullptr, S,
        nullptr, nullptr, nullptr,
        4096, 4096, 1024, 1024, 0.03125f, 32, 32, 0);
    // 5) softmax rows in place (bf16)
    softmax_bf16<<<4096, 256, 0, stream>>>(S);
    // 6) partials = P @ V  (split-K; z=0 writes straight to out)
    if (SK == 4) {
        gemm128<float, 2><<<dim3(4, 32, 4), 512, 0, stream>>>(
            S, Vt, nullptr, nullptr, nullptr, out, p1, p2, p3,
            4096, 1024, 4096, 4096, 1.f, 32, 32, 1024);
        combine<<<1024, 256, 0, stream>>>(out, p1, p2, p3, 3);
    } else {
        gemm128<float, 2><<<dim3(4, 32, 3), 512, 0, stream>>>(
            S, Vt, nullptr, nullptr, nullptr, out, p1, p2, nullptr,
            4096, 1024, 4096, 4096, 1.f, 42, 44, 1344);
        combine<<<1024, 256, 0, stream>>>(out, p1, p2, nullptr, 2);
    }
}